// Round 10
// baseline (135.540 us; speedup 1.0000x reference)
//
#include <hip/hip_runtime.h>
#include <hip/hip_bf16.h>

// Problem constants: B=16, D=256, T_enc=512, T_dec=2048
#define NB 16
#define ND 256
#define NK 512    // T_enc (contraction dim)
#define NT 2048   // T_dec (output cols)

// HYBRID staging (R9 post-mortem):
//  A (x): L2-resident, short-latency -> R0's lean path verbatim:
//         float4 load -> cvt -> bf16 LDS [128][RSA=40], ds_read_b128 frags,
//         zero cvt in compute. Single-buffered (rebuilt each step).
//  B (path): 64MB stream, ~2000cyc loaded HBM latency -> 4-buffer fp32 DMA
//         (global_load_lds, R7-verified addressing+swizzle), staged 3 STEPS
//         AHEAD with counted vmcnt(8) (R9's 1-step lookahead was the miss).
// Two barriers/step as the base. LDS 10KB + 64KB = 75.8KB -> 2 blocks/CU.
#define BM 128
#define BN 128
#define BK 32
#define NSTEP (NK / BK)   // 16
#define RSA 40   // A LDS row stride in bf16 (80B: 16B-aligned for b128, 2-way banks)

typedef __attribute__((ext_vector_type(8))) short short8;   // 8 bf16 = 4 VGPRs
typedef __attribute__((ext_vector_type(4))) float f32x4;    // MFMA accumulator

union BF2U { __hip_bfloat162 h; unsigned int u; };
union S8U4 { short8 v; unsigned int u[4]; };

__device__ inline unsigned int pack2bf(float a, float b) {
    BF2U c; c.h = __float22bfloat162_rn(make_float2(a, b));
    return c.u;
}

// 16B-per-lane async global->LDS DMA. LDS dest = wave-uniform base + lane*16.
#define GLOAD_LDS(g, l) __builtin_amdgcn_global_load_lds(                     \
    (const __attribute__((address_space(1))) void*)(g),                       \
    (__attribute__((address_space(3))) void*)(l), 16, 0, 0)

#define VMCNT8() asm volatile("s_waitcnt vmcnt(8)" ::: "memory")
#define VMCNT4() asm volatile("s_waitcnt vmcnt(4)" ::: "memory")
#define VMCNT0() asm volatile("s_waitcnt vmcnt(0)" ::: "memory")
#define LGKM0()  asm volatile("s_waitcnt lgkmcnt(0)" ::: "memory")
#define BAR()    __builtin_amdgcn_s_barrier()
#define SCHED0() __builtin_amdgcn_sched_barrier(0)

__global__ __launch_bounds__(256, 2)
void bmm_bf16_mfma(const float* __restrict__ x, const float* __restrict__ path,
                   float* __restrict__ out) {
    // ---- Chunked XCD swizzle (bijective: 512 % 8 == 0), R6-verified.
    const int id  = blockIdx.x;                 // 0..511
    const int swz = (id & 7) * 64 + (id >> 3);
    const int b   = swz >> 5;                   // batch 0..15
    const int rem = swz & 31;
    const int n0  = (rem >> 1) * BN;            // 16 n-blocks
    const int m0  = (rem & 1)  * BM;            // 2 m-blocks

    const int t    = threadIdx.x;
    const int lane = t & 63;
    const int wv   = t >> 6;          // wave id 0..3
    const int wr   = (wv >> 1) * 64;  // wave row offset in tile
    const int wc   = (wv & 1) * 64;   // wave col offset in tile
    const int q    = lane >> 4;       // quad 0..3
    const int lm   = lane & 15;

    __shared__ unsigned short As[BM * RSA];  // A bf16, single-buffered (10 KB)
    __shared__ float Bv[4 * 4096];           // B fp32, 4 step-buffers (64 KB)

    const float* xg = x    + ((size_t)b * ND + m0) * NK;   // A tile base
    const float* pg = path + (size_t)b * NK * NT + n0;     // B tile base

    // ---- B DMA pointers (R7-verified): chunk c = k-rows c*2..c*2+1 of the
    // 32x128 fp32 step-tile; lane covers (k_off = l>>5, 16B slot = l&31);
    // source col-slot pre-swizzled s ^ (((k>>3)&1)<<2) so compute reads fold
    // to colB[nt] = wc + ((nt^(q&1))*16) + lm (<=2-way banks).
    const float* gB[4];
    float* lB[4];
#pragma unroll
    for (int i = 0; i < 4; ++i) {
        const int c  = wv * 4 + i;             // chunk 0..15, 1 KiB each
        const int kb = c * 2 + (lane >> 5);
        const int sb = (lane & 31) ^ (((kb >> 3) & 1) << 2);
        gB[i] = pg + (size_t)kb * NT + sb * 4;
        lB[i] = &Bv[c * 256];
    }
    auto stageB = [&](int bi) {                // bi = buffer 0..3
#pragma unroll
        for (int i = 0; i < 4; ++i) { GLOAD_LDS(gB[i], lB[i] + bi * 4096); gB[i] += (size_t)BK * NT; }
    };

    // ---- A staging (R0-verified): float4 loads -> bf16 -> b64 LDS writes.
    auto stageA = [&](int k0) {
#pragma unroll
        for (int i = 0; i < 4; ++i) {
            int f   = t + i * 256;       // 0..1023 float4s
            int row = f >> 3;            // 8 float4 per 32-wide row
            int c4  = f & 7;
            float4 v = *reinterpret_cast<const float4*>(xg + (size_t)row * NK + k0 + c4 * 4);
            uint2 p;
            p.x = pack2bf(v.x, v.y);
            p.y = pack2bf(v.z, v.w);
            *reinterpret_cast<uint2*>(&As[row * RSA + c4 * 4]) = p;
        }
    };

    int colB[4];
#pragma unroll
    for (int nt = 0; nt < 4; ++nt)
        colB[nt] = wc + ((nt ^ (q & 1)) * 16) + lm;

    f32x4 acc[4][4];
#pragma unroll
    for (int i = 0; i < 4; ++i)
#pragma unroll
        for (int j = 0; j < 4; ++j)
            acc[i][j] = (f32x4){0.f, 0.f, 0.f, 0.f};

    auto compute = [&](int bi) {
        short8 af[4], bfr[4];
#pragma unroll
        for (int mt = 0; mt < 4; ++mt)
            af[mt] = *reinterpret_cast<const short8*>(
                &As[(wr + mt * 16 + lm) * RSA + q * 8]);  // lean bf16 b128 (R0)
#pragma unroll
        for (int nt = 0; nt < 4; ++nt) {
            const float* bp = &Bv[bi * 4096 + q * 1024 + colB[nt]];
            float f0 = bp[0 * 128], f1 = bp[1 * 128], f2 = bp[2 * 128], f3 = bp[3 * 128];
            float f4 = bp[4 * 128], f5 = bp[5 * 128], f6 = bp[6 * 128], f7 = bp[7 * 128];
            S8U4 s;
            s.u[0] = pack2bf(f0, f1);
            s.u[1] = pack2bf(f2, f3);
            s.u[2] = pack2bf(f4, f5);
            s.u[3] = pack2bf(f6, f7);
            bfr[nt] = s.v;
        }
        // Swapped operands (harness-verified R1-R3,R6,R7,R9): lane (q,lm)
        // holds C[m = lm][n = q*4 + r] -> f32x4 epilogue stores.
#pragma unroll
        for (int mt = 0; mt < 4; ++mt)
#pragma unroll
            for (int nt = 0; nt < 4; ++nt)
                acc[mt][nt] = __builtin_amdgcn_mfma_f32_16x16x32_bf16(
                    bfr[nt], af[mt], acc[mt][nt], 0, 0, 0);
    };

    // ---- Pipeline: B staged 3 steps ahead (4 stages x 4 DMA/wave in flight
    // max; vmcnt(8) releases exactly the oldest stage). A rebuilt per step
    // inside the same barrier pair (its loads drain via cvt data-deps).
    stageB(0); stageB(1); stageB(2); SCHED0();           // steps 0,1,2 in flight

    for (int s = 0; s < NSTEP - 3; ++s) {                // s = 0..12
        VMCNT8(); SCHED0();          // own-wave B[s] landed (keeps s+1,s+2)
        stageA(s * BK);              // A loads+cvt+ds_write (self-draining)
        LGKM0();                     // A writes visible
        BAR(); SCHED0();             // all waves: A written, B[s] landed
        stageB((s + 3) & 3);         // buf (s+3)%4 free since iter s-1's compute
        compute(s & 3);
        BAR(); SCHED0();             // all done reading As before next overwrite
    }
    // Tail: s = 13 (outstanding B13,14,15), 14 (B14,15), 15 (B15)
    VMCNT8(); SCHED0(); stageA(13 * BK); LGKM0(); BAR(); SCHED0();
    compute(1); BAR(); SCHED0();
    VMCNT4(); SCHED0(); stageA(14 * BK); LGKM0(); BAR(); SCHED0();
    compute(2); BAR(); SCHED0();
    VMCNT0(); SCHED0(); stageA(15 * BK); LGKM0(); BAR(); SCHED0();
    compute(3);

    // ---- Epilogue: lane (q,lm) holds rows m=lm, cols q*4+0..3 (verified)
    float* og = out + ((size_t)b * ND + m0 + wr) * NT + n0 + wc;
#pragma unroll
    for (int mt = 0; mt < 4; ++mt)
#pragma unroll
        for (int nt = 0; nt < 4; ++nt)
            *reinterpret_cast<f32x4*>(
                &og[(size_t)(mt * 16 + lm) * NT + nt * 16 + q * 4]) = acc[mt][nt];
}

extern "C" void kernel_launch(void* const* d_in, const int* in_sizes, int n_in,
                              void* d_out, int out_size, void* d_ws, size_t ws_size,
                              hipStream_t stream) {
    const float* x    = (const float*)d_in[0];   // [16, 256, 512]
    const float* path = (const float*)d_in[1];   // [16, 512, 2048]
    float* out        = (float*)d_out;           // [16, 256, 2048]
    dim3 grid(512);                              // 2 m * 16 n * 16 b, 1D for swizzle
    dim3 block(256);
    bmm_bf16_mfma<<<grid, block, 0, stream>>>(x, path, out);
}